// Round 2
// baseline (54.771 us; speedup 1.0000x reference)
//
#include <hip/hip_runtime.h>

// CWT via truncated direct correlation.
// Reference: y[b, ch, n], ch in [0,128): uses x[b, ch%4, :] and Morlet wavelet
// (ch%32). Since 4 | 32, channels (s, s+32, s+64, s+96) are identical ->
// compute 32 unique channels, store 4 copies.
//   y[n] = sum_t x[n + t - 8191] * wav[t],  wav[t] = exp(-t^2/2sig^2) e^{2pi i f t}
// truncated at t >= ceil(7*sigma)+1 (envelope < e^-24.5; abs threshold 0.445).
// For n < 8191 - T all x indices are negative (zero pad) -> y == 0 exactly.
//
// Output layout is chosen at launch from out_size (the harness has no complex
// dtype branch, so d_out may hold either the float32 (re,im)-interleaved view
// [out_size = B*128*N*2] or a real-only float32 array [out_size = B*128*N]).

#define NPIX   16384      // H*W
#define NSCALE 32
#define NCH    4
#define TPAD   512        // padded max taps (scale=64 -> T=429)
#define RPT    4          // n-values per thread
#define BLK    256        // threads per block
#define NBLK   (BLK*RPT)  // 1024 n per block
#define NTILE  (NPIX/NBLK)
#define LHALF  8191       // (K-1)//2
#define ALPHA  7.0f
#define PI_F   3.14159265358979f

template <int MODE>  // 0: complex64 interleaved floats; 1: real-part-only f32
__global__ __launch_bounds__(BLK) void cwt_kernel(
    const float* __restrict__ x,
    const float* __restrict__ scales,
    float* __restrict__ out)
{
    __shared__ float4 xs4s[(NBLK + TPAD) / 4];  // 1536 floats = 6 KB
    __shared__ float4 tsh4s[TPAD / 2];          // 512 taps as (c,s,c,s) = 4 KB

    const int tid  = threadIdx.x;
    const int tile = blockIdx.x;
    const int s    = blockIdx.y;   // unique channel / scale index
    const int b    = blockIdx.z;

    const float scale = scales[s];
    const float f     = 1.0f / scale;
    const float sigma = 6.0f * scale / (2.0f * PI_F);
    int T = (int)ceilf(ALPHA * sigma) + 1;
    if (T > TPAD) T = TPAD;

    const int n0 = tile * NBLK;
    const int nb = n0 + tid * RPT;

    // per-(b,s,n-range) output base in FLOAT units, + channel-copy stride
    const size_t rowElems = ((size_t)b * (NSCALE * NCH) + s) * NPIX + nb;
    float* obase = out + (MODE == 0 ? rowElems * 2 : rowElems);
    const size_t cstride = (MODE == 0) ? (size_t)NSCALE * NPIX * 2
                                       : (size_t)NSCALE * NPIX;

    // ---- fast path: whole tile in the zero region (max x index < 0) ----
    if (n0 + NBLK - 1 - LHALF + T - 1 < 0) {
        const float4 z = {0.f, 0.f, 0.f, 0.f};
        #pragma unroll
        for (int q = 0; q < 4; ++q) {
            float4* p = reinterpret_cast<float4*>(obase + (size_t)q * cstride);
            p[0] = z;
            if (MODE == 0) p[1] = z;
        }
        return;
    }

    // ---- build taps in LDS: 2 taps per thread ----
    {
        const float inv2s2 = 1.0f / (2.0f * sigma * sigma);
        const int t = tid * 2;
        float4 w = {0.f, 0.f, 0.f, 0.f};
        if (t < T) {
            const float tf = (float)t;
            const float g  = expf(-tf * tf * inv2s2);
            float sn, cs;
            sincosf(2.0f * PI_F * (f * tf), &sn, &cs);
            w.x = g * cs; w.y = g * sn;
        }
        if (t + 1 < T) {
            const float tf = (float)(t + 1);
            const float g  = expf(-tf * tf * inv2s2);
            float sn, cs;
            sincosf(2.0f * PI_F * (f * tf), &sn, &cs);
            w.z = g * cs; w.w = g * sn;
        }
        tsh4s[tid] = w;
    }

    // ---- stage x window: xs[i] = x[n0 - LHALF + i], zero-padded ----
    {
        const float* xrow = x + ((size_t)b * NCH + (s & 3)) * NPIX;
        const int base = n0 - LHALF;
        float* xs = reinterpret_cast<float*>(xs4s);
        for (int i = tid; i < NBLK + TPAD; i += BLK) {
            const int xi = base + i;
            xs[i] = ((unsigned)xi < (unsigned)NPIX) ? xrow[xi] : 0.0f;
        }
    }
    __syncthreads();

    // ---- main loop: 4 taps/iter, rolling float4 window, 32 FMA/iter ----
    const int T4 = (T + 3) & ~3;      // taps zero-padded, safe to overrun
    float ar[RPT] = {0.f, 0.f, 0.f, 0.f};
    float ai[RPT] = {0.f, 0.f, 0.f, 0.f};
    float4 win = xs4s[tid];
    for (int t0 = 0; t0 < T4; t0 += 4) {
        const float4 nxt = xs4s[tid + (t0 >> 2) + 1];
        const float4 w01 = tsh4s[(t0 >> 1)];
        const float4 w23 = tsh4s[(t0 >> 1) + 1];
        const float e[8] = {win.x, win.y, win.z, win.w,
                            nxt.x, nxt.y, nxt.z, nxt.w};
        const float c[4]  = {w01.x, w01.z, w23.x, w23.z};
        const float sn[4] = {w01.y, w01.w, w23.y, w23.w};
        #pragma unroll
        for (int j = 0; j < 4; ++j) {
            #pragma unroll
            for (int r = 0; r < RPT; ++r) {
                ar[r] = fmaf(c[j],  e[r + j], ar[r]);
                ai[r] = fmaf(sn[j], e[r + j], ai[r]);
            }
        }
        win = nxt;
    }

    // ---- store: 4 channel copies ----
    if (MODE == 0) {
        const float4 v0 = {ar[0], ai[0], ar[1], ai[1]};
        const float4 v1 = {ar[2], ai[2], ar[3], ai[3]};
        #pragma unroll
        for (int q = 0; q < 4; ++q) {
            float4* p = reinterpret_cast<float4*>(obase + (size_t)q * cstride);
            p[0] = v0; p[1] = v1;
        }
    } else {
        const float4 v = {ar[0], ar[1], ar[2], ar[3]};
        #pragma unroll
        for (int q = 0; q < 4; ++q) {
            *reinterpret_cast<float4*>(obase + (size_t)q * cstride) = v;
        }
    }
}

extern "C" void kernel_launch(void* const* d_in, const int* in_sizes, int n_in,
                              void* d_out, int out_size, void* d_ws, size_t ws_size,
                              hipStream_t stream) {
    const float* x      = (const float*)d_in[0];
    const float* scales = (const float*)d_in[1];
    float* out          = (float*)d_out;

    const int B = in_sizes[0] / (NCH * NPIX);   // 4
    const size_t fullComplexFloats = (size_t)B * NSCALE * NCH * NPIX * 2;

    dim3 grid(NTILE, NSCALE, B);
    if ((size_t)out_size >= fullComplexFloats) {
        cwt_kernel<0><<<grid, BLK, 0, stream>>>(x, scales, out);
    } else {
        cwt_kernel<1><<<grid, BLK, 0, stream>>>(x, scales, out);
    }
}

// Round 5
// 48.210 us; speedup vs baseline: 1.1361x; 1.1361x over previous
//
#include <hip/hip_runtime.h>

// CWT via truncated direct correlation — REAL PART ONLY.
// Round-2 bench proved the harness validates out_size = B*128*N float32 = the
// real part of the complex64 reference (numpy complex->float32 cast). x is
// real, so y_re[n] = sum_t x[n + t - 8191] * g(t)*cos(2*pi*f*t), with
// g(t)=exp(-t^2/2sigma^2), sigma=6*scale/2pi, truncated at t >= ceil(7sigma)+1
// (envelope < e^-24.5; abs threshold 0.445). Channels: ch%4 picks x-row,
// ch%32 picks wavelet; 4|32 -> compute 32 unique channels, store 4 copies.
// y == 0 exactly for n < 8191 - (T-1)  (only zero-padding under the window).
//
// Perf structure: BLK=128 threads, 512 outputs/block -> 4096 blocks, 6 KB LDS
// -> ALL blocks co-resident (16/CU = wave cap), no dispatch tail, load
// imbalance across scales absorbed by 32 waves/CU of statistically-mixed work.

#define NPIX   16384      // H*W
#define NSCALE 32
#define NCH    4
#define TPAD   512        // padded max taps (scale=64 -> T=429)
#define RPT    4          // n-values per thread
#define BLK    128        // threads per block
#define NBLK   (BLK*RPT)  // 512 n per block
#define NTILE  (NPIX/NBLK)// 32
#define LHALF  8191       // (K-1)//2
#define ALPHA  7.0f
#define PI_F   3.14159265358979f

__global__ __launch_bounds__(BLK) void cwt_kernel(
    const float* __restrict__ x,
    const float* __restrict__ scales,
    float* __restrict__ out)
{
    __shared__ float xs[NBLK + TPAD];   // 1024 floats = 4 KB
    __shared__ float taps[TPAD];        // 512 floats  = 2 KB

    const int tid  = threadIdx.x;
    const int tile = blockIdx.x;
    const int s    = blockIdx.y;   // unique channel / scale index
    const int b    = blockIdx.z;

    const float scale = scales[s];
    const float f     = 1.0f / scale;
    const float sigma = 6.0f * scale / (2.0f * PI_F);
    int T = (int)ceilf(ALPHA * sigma) + 1;
    if (T > TPAD) T = TPAD;

    const int n0 = tile * NBLK;
    const int nb = n0 + tid * RPT;

    // output base (float units) + channel-copy stride
    float* obase = out + ((size_t)b * (NSCALE * NCH) + s) * NPIX + nb;
    const size_t cstride = (size_t)NSCALE * NPIX;

    // ---- fast path: whole tile in the exact-zero region ----
    if (n0 + NBLK - 1 + T - 1 - LHALF < 0) {
        const float4 z = {0.f, 0.f, 0.f, 0.f};
        #pragma unroll
        for (int q = 0; q < 4; ++q)
            *reinterpret_cast<float4*>(obase + (size_t)q * cstride) = z;
        return;
    }

    // ---- build real taps in LDS (gauss * cos), zero-padded to TPAD ----
    {
        const float inv2s2 = 1.0f / (2.0f * sigma * sigma);
        const float w2pi   = 2.0f * PI_F * f;
        #pragma unroll
        for (int k = 0; k < TPAD / BLK; ++k) {
            const int t = tid + k * BLK;
            float tap = 0.0f;
            if (t < T) {
                const float tf = (float)t;
                tap = __expf(-tf * tf * inv2s2) * __cosf(w2pi * tf);
            }
            taps[t] = tap;
        }
    }

    // ---- stage x window: xs[i] = x[n0 - LHALF + i], zero-padded ----
    {
        const float* xrow = x + ((size_t)b * NCH + (s & 3)) * NPIX;
        const int base = n0 - LHALF;
        #pragma unroll
        for (int k = 0; k < (NBLK + TPAD) / BLK; ++k) {
            const int i  = tid + k * BLK;
            const int xi = base + i;
            xs[i] = ((unsigned)xi < (unsigned)NPIX) ? xrow[xi] : 0.0f;
        }
    }
    __syncthreads();

    // ---- main loop: 4 taps/iter, rolling float4 window, 16 FMA/iter ----
    const int T4 = (T + 3) & ~3;   // taps zero-padded -> safe overrun
    float ar0 = 0.f, ar1 = 0.f, ar2 = 0.f, ar3 = 0.f;
    const float4* xs4 = reinterpret_cast<const float4*>(xs);
    const float4* tp4 = reinterpret_cast<const float4*>(taps);
    float4 win = xs4[tid];
    for (int t0 = 0; t0 < T4; t0 += 4) {
        const float4 nxt = xs4[tid + (t0 >> 2) + 1];
        const float4 w   = tp4[t0 >> 2];
        const float e0 = win.x, e1 = win.y, e2 = win.z, e3 = win.w;
        const float e4 = nxt.x, e5 = nxt.y, e6 = nxt.z;
        ar0 = fmaf(w.x, e0, fmaf(w.y, e1, fmaf(w.z, e2, fmaf(w.w, e3, ar0))));
        ar1 = fmaf(w.x, e1, fmaf(w.y, e2, fmaf(w.z, e3, fmaf(w.w, e4, ar1))));
        ar2 = fmaf(w.x, e2, fmaf(w.y, e3, fmaf(w.z, e4, fmaf(w.w, e5, ar2))));
        ar3 = fmaf(w.x, e3, fmaf(w.y, e4, fmaf(w.z, e5, fmaf(w.w, e6, ar3))));
        win = nxt;
    }

    // ---- store 4 channel copies (coalesced float4) ----
    const float4 v = {ar0, ar1, ar2, ar3};
    #pragma unroll
    for (int q = 0; q < 4; ++q)
        *reinterpret_cast<float4*>(obase + (size_t)q * cstride) = v;
}

extern "C" void kernel_launch(void* const* d_in, const int* in_sizes, int n_in,
                              void* d_out, int out_size, void* d_ws, size_t ws_size,
                              hipStream_t stream) {
    const float* x      = (const float*)d_in[0];
    const float* scales = (const float*)d_in[1];
    float* out          = (float*)d_out;

    const int B = in_sizes[0] / (NCH * NPIX);   // 4
    dim3 grid(NTILE, NSCALE, B);
    cwt_kernel<<<grid, BLK, 0, stream>>>(x, scales, out);
}

// Round 6
// 41.325 us; speedup vs baseline: 1.3254x; 1.1666x over previous
//
#include <hip/hip_runtime.h>

// CWT via truncated direct correlation — REAL PART ONLY (round-2 bench proved
// the harness validates out_size = B*128*N float32 = real part of complex64).
//   y[n] = sum_t x[n+t-8191] * g(t)*cos(2*pi*f*t),  g=exp(-t^2/2sig^2),
//   sigma = 6*scale/2pi, truncated at T = ceil(7*sigma)+1 (abs thr 0.445).
// ch%4 picks x row, ch%32 picks wavelet; 4|32 -> 32 unique channels, 4 copies.
// y == 0 exactly for n <= 8191 - T (pure zero-padding under the window).
//
// ROUND-5 LESSON (counters): VALUBusy 12%, Occ 21% -> all work fits in ~6 us
// of issue; 47 us duration = tail of scale-31 blocks (108 iters) draining
// alone. Fix = BLOCK-LEVEL BALANCE: pair scale s with 31-s (linspace =>
// T_s + T_{31-s} ~ 437 = const). Each block: one tile, two phases (scale A,
// scale B), equal work for EVERY working block -> no tail.

#define NPIX   16384      // H*W
#define NSCALE 32
#define NCH    4
#define TPAD   512        // padded max taps (scale=64 -> T=429)
#define RPT    4          // n-values per thread
#define BLK    256        // threads per block
#define NBLK   (BLK*RPT)  // 1024 n per block
#define NTILE  (NPIX/NBLK)// 16
#define LHALF  8191       // (K-1)//2
#define ALPHA  7.0f
#define PI_F   3.14159265358979f

__global__ __launch_bounds__(BLK) void cwt_kernel(
    const float* __restrict__ x,
    const float* __restrict__ scales,
    float* __restrict__ out)
{
    __shared__ float xs[NBLK + TPAD];   // 1536 floats = 6 KB
    __shared__ float taps[TPAD];        // 512 floats  = 2 KB

    const int tid  = threadIdx.x;
    const int tile = blockIdx.x;
    const int b    = blockIdx.z;

    const int n0 = tile * NBLK;
    const int nb = n0 + tid * RPT;
    const size_t cstride = (size_t)NSCALE * NPIX;

    for (int phase = 0; phase < 2; ++phase) {
        const int s = (phase == 0) ? (int)blockIdx.y : (NSCALE - 1 - (int)blockIdx.y);

        const float scale = scales[s];
        const float f     = 1.0f / scale;
        const float sigma = 6.0f * scale / (2.0f * PI_F);
        int T = (int)ceilf(ALPHA * sigma) + 1;
        if (T > TPAD) T = TPAD;

        float* obase = out + ((size_t)b * (NSCALE * NCH) + s) * NPIX + nb;

        // block-uniform: is this whole tile in the exact-zero region?
        const bool zero_tile = (n0 + NBLK - 1 + T - 1 - LHALF < 0);

        if (zero_tile) {
            const float4 z = {0.f, 0.f, 0.f, 0.f};
            #pragma unroll
            for (int q = 0; q < 4; ++q)
                *reinterpret_cast<float4*>(obase + (size_t)q * cstride) = z;
        } else {
            // ---- stage real taps (gauss * cos), zero-padded to TPAD ----
            {
                const float inv2s2 = 1.0f / (2.0f * sigma * sigma);
                const float w2pi   = 2.0f * PI_F * f;
                #pragma unroll
                for (int k = 0; k < TPAD / BLK; ++k) {
                    const int t = tid + k * BLK;
                    float tap = 0.0f;
                    if (t < T) {
                        const float tf = (float)t;
                        tap = __expf(-tf * tf * inv2s2) * __cosf(w2pi * tf);
                    }
                    taps[t] = tap;
                }
            }
            // ---- stage x window: xs[i] = x[n0 - LHALF + i], zero-padded ----
            {
                const float* xrow = x + ((size_t)b * NCH + (s & 3)) * NPIX;
                const int base = n0 - LHALF;
                #pragma unroll
                for (int k = 0; k < (NBLK + TPAD) / BLK; ++k) {
                    const int i  = tid + k * BLK;
                    const int xi = base + i;
                    xs[i] = ((unsigned)xi < (unsigned)NPIX) ? xrow[xi] : 0.0f;
                }
            }
            __syncthreads();

            // ---- main loop: 4 taps/iter, rolling float4 window ----
            const int T4 = (T + 3) & ~3;   // taps zero-padded -> safe overrun
            float ar0 = 0.f, ar1 = 0.f, ar2 = 0.f, ar3 = 0.f;
            const float4* xs4 = reinterpret_cast<const float4*>(xs);
            const float4* tp4 = reinterpret_cast<const float4*>(taps);
            float4 win = xs4[tid];
            for (int t0 = 0; t0 < T4; t0 += 4) {
                const float4 nxt = xs4[tid + (t0 >> 2) + 1];
                const float4 w   = tp4[t0 >> 2];
                const float e0 = win.x, e1 = win.y, e2 = win.z, e3 = win.w;
                const float e4 = nxt.x, e5 = nxt.y, e6 = nxt.z;
                ar0 = fmaf(w.x, e0, fmaf(w.y, e1, fmaf(w.z, e2, fmaf(w.w, e3, ar0))));
                ar1 = fmaf(w.x, e1, fmaf(w.y, e2, fmaf(w.z, e3, fmaf(w.w, e4, ar1))));
                ar2 = fmaf(w.x, e2, fmaf(w.y, e3, fmaf(w.z, e4, fmaf(w.w, e5, ar2))));
                ar3 = fmaf(w.x, e3, fmaf(w.y, e4, fmaf(w.z, e5, fmaf(w.w, e6, ar3))));
                win = nxt;
            }

            // ---- store 4 channel copies (coalesced float4) ----
            const float4 v = {ar0, ar1, ar2, ar3};
            #pragma unroll
            for (int q = 0; q < 4; ++q)
                *reinterpret_cast<float4*>(obase + (size_t)q * cstride) = v;
        }

        // block-uniform path: safe barrier before next phase re-stages LDS
        __syncthreads();
    }
}

extern "C" void kernel_launch(void* const* d_in, const int* in_sizes, int n_in,
                              void* d_out, int out_size, void* d_ws, size_t ws_size,
                              hipStream_t stream) {
    const float* x      = (const float*)d_in[0];
    const float* scales = (const float*)d_in[1];
    float* out          = (float*)d_out;

    const int B = in_sizes[0] / (NCH * NPIX);   // 4
    dim3 grid(NTILE, NSCALE / 2, B);            // 16 x 16 x 4 = 1024 blocks
    cwt_kernel<<<grid, BLK, 0, stream>>>(x, scales, out);
}

// Round 7
// 32.660 us; speedup vs baseline: 1.6770x; 1.2653x over previous
//
#include <hip/hip_runtime.h>

// CWT, truncated direct correlation, REAL PART ONLY (harness validates
// out_size = B*128*N float32 = real part of the complex64 reference).
//   y[n] = sum_t x[n+t-8191] * g(t)*cos(2*pi*f*t),  g = exp(-t^2/2sigma^2),
//   sigma = 6*scale/2pi, T = ceil(7*sigma)+1 taps (abs threshold 0.445).
// ch%4 -> x row, ch%32 -> wavelet; 4|32 -> 32 unique channels, 4 copies.
// y == 0 exactly for n < 8192 - T; since max T = 429, n < 7168 is zero for
// ALL scales -> zero-filled by compute blocks (no zero-only blocks).
//
// R6 lessons: (a) grid 16x16x4 aliased tile==CU%16 -> 112/256 CUs idle;
// (b) 4-tap loop exposed LDS latency per iter. Fix: 2304 identical blocks
// (= exactly 9/CU), scale-pairing (T_s + T_{31-s} ~ 437 = const), and
// 16-tap super-iterations (8 batched ds_reads, ONE wait, 64 unrolled FMAs).

#define NPIX   16384
#define NSCALE 32
#define NCH    4
#define TPAD   512        // padded taps (max T = 429)
#define BLK    64         // one wave per block
#define RPT    4
#define NBLK   (BLK*RPT)  // 256 outputs per block
#define WTILE0 28         // first working tile (n0 = 7168)
#define NWTILE 36         // tiles 28..63
#define NZTILE 28         // zero tiles per scale (n < 7168)
#define LHALF  8191
#define ALPHA  7.0f
#define PI_F   3.14159265358979f

__global__ __launch_bounds__(BLK) void cwt_kernel(
    const float* __restrict__ x,
    const float* __restrict__ scales,
    float* __restrict__ out)
{
    __shared__ float xs[NBLK + TPAD];   // 768 floats = 3 KB
    __shared__ float taps[TPAD];        // 512 floats = 2 KB

    const int lane = threadIdx.x;
    const int w    = blockIdx.x;              // 0..35 -> tile 28+w
    const int p    = blockIdx.y;              // scale pair
    const int b    = blockIdx.z;

    const int tile = WTILE0 + w;
    const int n0   = tile * NBLK;
    const size_t cstride = (size_t)NSCALE * NPIX;

    // ---- zero-region stores: block w writes zero-tiles z = w, w+36 (<56) ----
    {
        const float4 z4 = {0.f, 0.f, 0.f, 0.f};
        #pragma unroll
        for (int zz = 0; zz < 2; ++zz) {
            const int z = w + zz * NWTILE;
            if (z < 2 * NZTILE) {
                const int sz    = (z < NZTILE) ? p : (NSCALE - 1 - p);
                const int tileZ = (z < NZTILE) ? z : z - NZTILE;
                float* zb = out + ((size_t)b * (NSCALE * NCH) + sz) * NPIX
                                + tileZ * NBLK + lane * 4;
                #pragma unroll
                for (int q = 0; q < 4; ++q)
                    *reinterpret_cast<float4*>(zb + (size_t)q * cstride) = z4;
            }
        }
    }

    const float4* xs4 = reinterpret_cast<const float4*>(xs);
    const float4* tp4 = reinterpret_cast<const float4*>(taps);

    for (int phase = 0; phase < 2; ++phase) {
        const int s = (phase == 0) ? p : (NSCALE - 1 - p);

        const float scale = scales[s];
        const float f     = 1.0f / scale;
        const float sigma = 6.0f * scale / (2.0f * PI_F);
        int T = (int)ceilf(ALPHA * sigma) + 1;
        if (T > TPAD) T = TPAD;

        // ---- stage taps (zero-padded to TPAD) ----
        {
            const float inv2s2 = 1.0f / (2.0f * sigma * sigma);
            const float w2pi   = 2.0f * PI_F * f;
            #pragma unroll
            for (int k = 0; k < TPAD / BLK; ++k) {
                const int t = lane + k * BLK;
                float tap = 0.0f;
                if (t < T) {
                    const float tf = (float)t;
                    tap = __expf(-tf * tf * inv2s2) * __cosf(w2pi * tf);
                }
                taps[t] = tap;
            }
        }
        // ---- stage x window xs[i] = x[n0 - LHALF + i] (zero-padded) ----
        {
            const float* xrow = x + ((size_t)b * NCH + (s & 3)) * NPIX;
            const int base = n0 - LHALF;
            #pragma unroll
            for (int k = 0; k < (NBLK + TPAD) / BLK; ++k) {
                const int i  = lane + k * BLK;
                const int xi = base + i;
                xs[i] = ((unsigned)xi < (unsigned)NPIX) ? xrow[xi] : 0.0f;
            }
        }
        __syncthreads();

        // ---- 16-tap super-iterations: 8 batched LDS reads, one wait, 64 FMA
        const int nG = (T + 15) >> 4;
        float a0 = 0.f, a1 = 0.f, a2 = 0.f, a3 = 0.f;
        float4 xw0 = xs4[lane];
        for (int g = 0; g < nG; ++g) {
            const int j = g * 4;
            const float4 x1 = xs4[lane + j + 1];
            const float4 x2 = xs4[lane + j + 2];
            const float4 x3 = xs4[lane + j + 3];
            const float4 x4 = xs4[lane + j + 4];
            const float4 w0 = tp4[j + 0];
            const float4 w1 = tp4[j + 1];
            const float4 w2 = tp4[j + 2];
            const float4 w3 = tp4[j + 3];

            const float e[20] = {xw0.x, xw0.y, xw0.z, xw0.w,
                                 x1.x, x1.y, x1.z, x1.w,
                                 x2.x, x2.y, x2.z, x2.w,
                                 x3.x, x3.y, x3.z, x3.w,
                                 x4.x, x4.y, x4.z, x4.w};
            const float wk[16] = {w0.x, w0.y, w0.z, w0.w,
                                  w1.x, w1.y, w1.z, w1.w,
                                  w2.x, w2.y, w2.z, w2.w,
                                  w3.x, w3.y, w3.z, w3.w};
            #pragma unroll
            for (int k = 0; k < 16; ++k) {
                a0 = fmaf(wk[k], e[k + 0], a0);
                a1 = fmaf(wk[k], e[k + 1], a1);
                a2 = fmaf(wk[k], e[k + 2], a2);
                a3 = fmaf(wk[k], e[k + 3], a3);
            }
            xw0 = x4;
        }

        // ---- store 4 channel copies ----
        float* obase = out + ((size_t)b * (NSCALE * NCH) + s) * NPIX
                           + n0 + lane * RPT;
        const float4 v = {a0, a1, a2, a3};
        #pragma unroll
        for (int q = 0; q < 4; ++q)
            *reinterpret_cast<float4*>(obase + (size_t)q * cstride) = v;

        __syncthreads();   // LDS safe to overwrite in next phase
    }
}

extern "C" void kernel_launch(void* const* d_in, const int* in_sizes, int n_in,
                              void* d_out, int out_size, void* d_ws, size_t ws_size,
                              hipStream_t stream) {
    const float* x      = (const float*)d_in[0];
    const float* scales = (const float*)d_in[1];
    float* out          = (float*)d_out;

    const int B = in_sizes[0] / (NCH * NPIX);   // 4
    dim3 grid(NWTILE, NSCALE / 2, B);           // 36 x 16 x 4 = 2304 blocks
    cwt_kernel<<<grid, BLK, 0, stream>>>(x, scales, out);
}